// Round 2
// baseline (567.091 us; speedup 1.0000x reference)
//
#include <hip/hip_runtime.h>

#define NLVL 14

__device__ __forceinline__ float fma4(float4 v, float4 w, float acc) {
    acc = fmaf(v.x, w.x, acc);
    acc = fmaf(v.y, w.y, acc);
    acc = fmaf(v.z, w.z, acc);
    return fmaf(v.w, w.w, acc);
}

// exclusive prefix over a 256-thread block, one atomicAdd per block.
__device__ __forceinline__ int block_scan_base(int mycnt, int* gcnt, int& myoff) {
    __shared__ int wsum[4];
    __shared__ int base;
    int lane = threadIdx.x & 63, wid = threadIdx.x >> 6;
    int scan = mycnt;
    #pragma unroll
    for (int d = 1; d < 64; d <<= 1) {
        int tv = __shfl_up(scan, d, 64);
        if (lane >= d) scan += tv;
    }
    if (lane == 63) wsum[wid] = scan;
    __syncthreads();
    if (threadIdx.x == 0) {
        int tot = 0;
        #pragma unroll
        for (int i = 0; i < 4; i++) { int tv = wsum[i]; wsum[i] = tot; tot += tv; }
        base = tot ? atomicAdd(gcnt, tot) : 0;
    }
    __syncthreads();
    myoff = wsum[wid] + scan - mycnt;
    return base;
}

// transpose ws (13,3,3,ci,co) -> wt (13*9, co, ci)
__global__ __launch_bounds__(256) void k_wt(const float* __restrict__ w, float* __restrict__ wt) {
    int t = blockIdx.x * 256 + threadIdx.x;
    if (t >= 13 * 9 * 32 * 32) return;
    int ci = t & 31, co = (t >> 5) & 31, tp = t >> 10;
    wt[(tp << 10) + (co << 5) + ci] = w[(tp << 10) + (ci << 5) + co];
}

// level-0 mask compaction: 16 elements/thread, coalesced float4/int4.
__global__ __launch_bounds__(256) void k_compact0(
    const float4* __restrict__ mask4, int* __restrict__ idxmap,
    int* __restrict__ coords, int* __restrict__ cnt, int cap) {
    int t = threadIdx.x;
    int g0 = blockIdx.x * 1024 + t;   // float4-group index; groups at g0 + j*256
    float4 m[4];
    #pragma unroll
    for (int j = 0; j < 4; j++) m[j] = mask4[g0 + j * 256];
    int pr[16];
    int mycnt = 0;
    #pragma unroll
    for (int j = 0; j < 4; j++) {
        pr[4 * j + 0] = m[j].x > 0.5f;
        pr[4 * j + 1] = m[j].y > 0.5f;
        pr[4 * j + 2] = m[j].z > 0.5f;
        pr[4 * j + 3] = m[j].w > 0.5f;
        mycnt += pr[4 * j] + pr[4 * j + 1] + pr[4 * j + 2] + pr[4 * j + 3];
    }
    int myoff;
    int base = block_scan_base(mycnt, cnt, myoff);
    int slot = base + myoff;
    #pragma unroll
    for (int j = 0; j < 4; j++) {
        int e0 = (g0 + j * 256) << 2;
        int wv[4];
        #pragma unroll
        for (int k = 0; k < 4; k++) {
            wv[k] = -1;
            if (pr[4 * j + k]) {
                int sl = slot++;
                if (sl < cap) { wv[k] = sl; coords[sl] = e0 + k; }
            }
        }
        *(int4*)(idxmap + e0) = make_int4(wv[0], wv[1], wv[2], wv[3]);
    }
}

// 2x2-max downsample + compaction of the next level's mask (vectorized).
__device__ __forceinline__ void down_part(
    const int* __restrict__ idx_in, int HinB,
    int* __restrict__ idx_out, int* __restrict__ coords_out, int* __restrict__ cnt_out,
    int HoutB, int cap_out) {
    int Hout = 1 << HoutB, Hin = 1 << HinB;
    int t = threadIdx.x;
    int o4 = blockIdx.x * 256 + t;           // int4-group of outputs
    int S4 = (Hout * Hout) >> 2;
    int pr0 = 0, pr1 = 0, pr2 = 0, pr3 = 0;
    int e0 = o4 << 2;
    if (o4 < S4) {
        int r = e0 >> HoutB, c0 = e0 & (Hout - 1);
        const int* row0 = idx_in + ((size_t)(2 * r) << HinB) + 2 * c0;
        const int* row1 = row0 + Hin;
        int4 a0 = *(const int4*)row0;
        int4 a1 = *(const int4*)(row0 + 4);
        int4 b0 = *(const int4*)row1;
        int4 b1 = *(const int4*)(row1 + 4);
        // only negative value in idxmap is -1 (all bits set) -> AND sign test
        pr0 = ((a0.x & a0.y & b0.x & b0.y) >= 0);
        pr1 = ((a0.z & a0.w & b0.z & b0.w) >= 0);
        pr2 = ((a1.x & a1.y & b1.x & b1.y) >= 0);
        pr3 = ((a1.z & a1.w & b1.z & b1.w) >= 0);
    }
    int mycnt = pr0 + pr1 + pr2 + pr3;
    int myoff;
    int base = block_scan_base(mycnt, cnt_out, myoff);
    if (o4 < S4) {
        int slot = base + myoff;
        int pr[4] = {pr0, pr1, pr2, pr3};
        int wv[4];
        #pragma unroll
        for (int k = 0; k < 4; k++) {
            wv[k] = -1;
            if (pr[k]) {
                int sl = slot++;
                if (sl < cap_out) { wv[k] = sl; coords_out[sl] = e0 + k; }
            }
        }
        *(int4*)(idx_out + e0) = make_int4(wv[0], wv[1], wv[2], wv[3]);
    }
}

// F1 = conv level0 (5x5, cin=1) + downsample level1
__global__ __launch_bounds__(256) void k_f1(
    int downBlocks,
    const int* __restrict__ idx0, int* __restrict__ idx1, int* __restrict__ coords1,
    int* __restrict__ cnt1, int cap1,
    const float* __restrict__ x, const float* __restrict__ w1,
    const int* __restrict__ coords0, const int* __restrict__ cnt0, int cap0,
    float* __restrict__ vals0) {
    if (blockIdx.x < downBlocks) {
        down_part(idx0, 11, idx1, coords1, cnt1, 10, cap1);
        return;
    }
    int tt = (blockIdx.x - downBlocks) * 256 + threadIdx.x;
    int s = tt >> 5, ch = tt & 31;
    int n = *cnt0; if (n > cap0) n = cap0;
    if (s >= n) return;
    int p = coords0[s];
    int r = p >> 11, c = p & 2047;
    float acc = 0.f;
    #pragma unroll
    for (int a = 0; a < 5; a++) {
        int rr = r + a - 2;
        if ((unsigned)rr >= 2048u) continue;
        #pragma unroll
        for (int b = 0; b < 5; b++) {
            int cc = c + b - 2;
            if ((unsigned)cc >= 2048u) continue;
            acc = fmaf(x[(rr << 11) + cc], w1[(a * 5 + b) * 32 + ch], acc);
        }
    }
    vals0[((size_t)s << 5) + ch] = fmaxf(acc, 0.f);
}

// Fi (i>=2) = conv level i-1 (weights in registers, cross-lane cin reduce)
//           + downsample level i
__global__ __launch_bounds__(256) void k_fused(
    int downBlocks,
    const int* __restrict__ idx_in, int HinB,
    int* __restrict__ idx_out, int* __restrict__ coords_out, int* __restrict__ cnt_out,
    int HoutB, int cap_out,
    const float* __restrict__ vprev, const int* __restrict__ idx_prev, int HpB,
    const float* __restrict__ wlvl,
    const int* __restrict__ coords_c, const int* __restrict__ cnt_c, int cap_c,
    float* __restrict__ vals_c, int HcB) {
    if (blockIdx.x < downBlocks) {
        down_part(idx_in, HinB, idx_out, coords_out, cnt_out, HoutB, cap_out);
        return;
    }
    __shared__ int s_j[16][9];
    int t = threadIdx.x;
    int ciq = t & 7, co = t >> 3;
    // 36 weights live in VGPRs for the whole kernel
    float4 wreg[9];
    #pragma unroll
    for (int tap = 0; tap < 9; tap++)
        wreg[tap] = *(const float4*)(wlvl + ((tap * 32 + co) << 5) + (ciq << 2));
    int Hc = 1 << HcB;
    unsigned Hp = 1u << HpB;
    int n = *cnt_c; if (n > cap_c) n = cap_c;
    int nGroups = (n + 15) >> 4;
    int cb = blockIdx.x - downBlocks;
    int stride = gridDim.x - downBlocks;
    for (int grp = cb; grp < nGroups; grp += stride) {
        int sg0 = grp << 4;
        __syncthreads();
        if (t < 144) {
            int g = t / 9, tap = t - g * 9;
            int s = sg0 + g;
            int j = -1;
            if (s < n) {
                int p = coords_c[s];
                int r = p >> HcB, c = p & (Hc - 1);
                int a = tap / 3, b = tap - a * 3;
                int rr = 2 * r + a - 1, cc = 2 * c + b - 1;
                if ((unsigned)rr < Hp && (unsigned)cc < Hp)
                    j = idx_prev[(rr << HpB) + cc];
            }
            s_j[g][tap] = j;
        }
        __syncthreads();
        #pragma unroll 2
        for (int g = 0; g < 16; g += 2) {
            int s0 = sg0 + g, s1 = s0 + 1;
            float a0 = 0.f, a1 = 0.f;
            #pragma unroll
            for (int tap = 0; tap < 9; tap++) {
                int j0 = s_j[g][tap];
                if (j0 >= 0)
                    a0 = fma4(*(const float4*)(vprev + ((size_t)j0 << 5) + (ciq << 2)), wreg[tap], a0);
                int j1 = s_j[g + 1][tap];
                if (j1 >= 0)
                    a1 = fma4(*(const float4*)(vprev + ((size_t)j1 << 5) + (ciq << 2)), wreg[tap], a1);
            }
            a0 += __shfl_xor(a0, 1); a0 += __shfl_xor(a0, 2); a0 += __shfl_xor(a0, 4);
            a1 += __shfl_xor(a1, 1); a1 += __shfl_xor(a1, 2); a1 += __shfl_xor(a1, 4);
            if (ciq == 0) {
                if (s0 < n) vals_c[((size_t)s0 << 5) + co] = fmaxf(a0, 0.f);
                if (s1 < n) vals_c[((size_t)s1 << 5) + co] = fmaxf(a1, 0.f);
            }
        }
    }
}

struct TailArgs {
    unsigned long long idx[NLVL], coord[NLVL], val[NLVL];
    int cap[NLVL];
    int Hb[NLVL];
};

__device__ __forceinline__ void tail_conv(int l, int n, char* ws, const TailArgs& ta,
                                          const float* __restrict__ wt,
                                          int ciq, int co, int sgrp) {
    int Hb = ta.Hb[l], H = 1 << Hb;
    int Hpb = ta.Hb[l - 1];
    unsigned Hp = 1u << Hpb;
    const float* vprev = (const float*)(ws + ta.val[l - 1]);
    const int* idx_prev = (const int*)(ws + ta.idx[l - 1]);
    const int* coords_l = (const int*)(ws + ta.coord[l]);
    float* vals_l = (float*)(ws + ta.val[l]);
    const float* wl = wt + (size_t)(l - 1) * 9 * 1024;
    float4 wreg[9];
    #pragma unroll
    for (int tap = 0; tap < 9; tap++)
        wreg[tap] = *(const float4*)(wl + ((tap * 32 + co) << 5) + (ciq << 2));
    for (int s = sgrp; s < n; s += 4) {
        int p = coords_l[s];
        int r = p >> Hb, c = p & (H - 1);
        float a0 = 0.f;
        #pragma unroll
        for (int tap = 0; tap < 9; tap++) {
            int a = tap / 3, b = tap - a * 3;
            int rr = 2 * r + a - 1, cc = 2 * c + b - 1;
            if ((unsigned)rr < Hp && (unsigned)cc < Hp) {
                int j = idx_prev[(rr << Hpb) + cc];
                if (j >= 0)
                    a0 = fma4(*(const float4*)(vprev + ((size_t)j << 5) + (ciq << 2)), wreg[tap], a0);
            }
        }
        a0 += __shfl_xor(a0, 1); a0 += __shfl_xor(a0, 2); a0 += __shfl_xor(a0, 4);
        if (ciq == 0) vals_l[((size_t)s << 5) + co] = fmaxf(a0, 0.f);
    }
    __threadfence_block();
    __syncthreads();
}

// conv8 + (down9,conv9) ... (down13,conv13) in ONE block.
__global__ __launch_bounds__(1024) void k_tail(char* __restrict__ ws, TailArgs ta,
                                               const float* __restrict__ wt,
                                               int* __restrict__ cnt) {
    __shared__ int s_cnt, s_n;
    int tid = threadIdx.x;
    int ciq = tid & 7, co = (tid >> 3) & 31, sgrp = tid >> 8;
    if (tid == 0) s_n = cnt[8];
    __syncthreads();
    int n = s_n; if (n > ta.cap[8]) n = ta.cap[8];
    tail_conv(8, n, ws, ta, wt, ciq, co, sgrp);
    for (int l = 9; l < NLVL; l++) {
        if (tid == 0) s_cnt = 0;
        __syncthreads();
        int H = 1 << ta.Hb[l], Hin = 1 << ta.Hb[l - 1];
        int S = H * H;
        const int* idx_in = (const int*)(ws + ta.idx[l - 1]);
        int* idx_o = (int*)(ws + ta.idx[l]);
        int* coords_o = (int*)(ws + ta.coord[l]);
        for (int p = tid; p < S; p += 1024) {
            int r = p >> ta.Hb[l], c = p & (H - 1);
            bool pred = false;
            #pragma unroll
            for (int dr = 0; dr < 2; dr++)
                #pragma unroll
                for (int dc = 0; dc < 2; dc++) {
                    int rr = 2 * r + dr, cc = 2 * c + dc;
                    if (rr < Hin && cc < Hin) pred |= (idx_in[rr * Hin + cc] >= 0);
                }
            int slot = -1;
            if (pred) slot = atomicAdd(&s_cnt, 1);
            idx_o[p] = slot;
            if (slot >= 0 && slot < ta.cap[l]) coords_o[slot] = p;
        }
        __threadfence_block();
        __syncthreads();
        n = s_cnt; if (n > ta.cap[l]) n = ta.cap[l];
        if (tid == 0) cnt[l] = s_cnt;
        tail_conv(l, n, ws, ta, wt, ciq, co, sgrp);
    }
}

struct PoolArgs {
    unsigned long long voff[NLVL];
    int cap[NLVL];
};

__global__ __launch_bounds__(256) void k_pool(const char* __restrict__ ws, PoolArgs pa,
                                              const int* __restrict__ cnt,
                                              float* __restrict__ poolsum) {
    __shared__ float red[256];
    int lvl = blockIdx.x >> 5;
    int chunk = blockIdx.x & 31;
    const float* vals = (const float*)(ws + pa.voff[lvl]);
    int n = cnt[lvl]; if (n > pa.cap[lvl]) n = pa.cap[lvl];
    int ch = threadIdx.x & 31;
    int s0 = chunk * 8 + (threadIdx.x >> 5);
    float acc = 0.f;
    for (int s = s0; s < n; s += 256)
        acc += vals[((size_t)s << 5) + ch];
    red[threadIdx.x] = acc;
    __syncthreads();
    if (threadIdx.x < 32) {
        float tot = 0.f;
        #pragma unroll
        for (int g = 0; g < 8; g++) tot += red[threadIdx.x + 32 * g];
        atomicAdd(&poolsum[lvl * 32 + threadIdx.x], tot);
    }
}

__global__ __launch_bounds__(256) void k_mlp(const float* __restrict__ poolsum,
                                             const int* __restrict__ cnt,
                                             const float* __restrict__ wm1, const float* __restrict__ bm1,
                                             const float* __restrict__ wm2, const float* __restrict__ bm2,
                                             float* __restrict__ out) {
    __shared__ float feat[448];
    __shared__ float h[256];
    int tid = threadIdx.x;
    for (int k = tid; k < 448; k += 256) {
        int lvl = k >> 5;
        float c = (float)cnt[lvl];
        if (c < 1.f) c = 1.f;
        feat[k] = poolsum[k] / c;
    }
    __syncthreads();
    float acc = bm1[tid];
    for (int k = 0; k < 448; k++)
        acc = fmaf(feat[k], wm1[k * 256 + tid], acc);
    h[tid] = fmaxf(acc, 0.f);
    __syncthreads();
    if (tid < 128) {
        float o = bm2[tid];
        for (int j = 0; j < 256; j++)
            o = fmaf(h[j], wm2[j * 128 + tid], o);
        out[tid] = o;
    }
}

extern "C" void kernel_launch(void* const* d_in, const int* in_sizes, int n_in,
                              void* d_out, int out_size, void* d_ws, size_t ws_size,
                              hipStream_t stream) {
    const float* x    = (const float*)d_in[0];
    const float* mask = (const float*)d_in[1];
    const float* w1   = (const float*)d_in[2];
    const float* ws_w = (const float*)d_in[3];
    const float* wm1  = (const float*)d_in[4];
    const float* bm1  = (const float*)d_in[5];
    const float* wm2  = (const float*)d_in[6];
    const float* bm2  = (const float*)d_in[7];
    float* out = (float*)d_out;
    char* ws = (char*)d_ws;

    static const int Hb[NLVL]   = {11, 10, 9, 8, 7, 6, 5, 4, 3, 2, 1, 0, 0, 0};
    // caps: >=15 sigma above expected masked counts per level (binomial)
    static const int caps[NLVL] = {45056, 43008, 43008, 34816, 16384, 4096,
                                   1024, 256, 64, 16, 4, 1, 1, 1};

    // ws layout
    size_t pool_off = 64;              // cnt[16] at 0, poolsum[448] at 64
    size_t wt_off = 2048;
    size_t off = wt_off + (size_t)13 * 9 * 32 * 32 * 4;   // 481280, 256-aligned
    size_t idx_off[NLVL], coord_off[NLVL], val_off[NLVL];
    for (int i = 0; i < NLVL; i++) {
        size_t S = (size_t)(1 << Hb[i]) * (1 << Hb[i]);
        idx_off[i] = off;   off += S * 4;                    off = (off + 255) & ~(size_t)255;
        coord_off[i] = off; off += (size_t)caps[i] * 4;      off = (off + 255) & ~(size_t)255;
        val_off[i] = off;   off += (size_t)caps[i] * 32 * 4; off = (off + 255) & ~(size_t)255;
    }

    int* cnt = (int*)ws;
    float* poolsum = (float*)(ws + pool_off);
    float* wt = (float*)(ws + wt_off);

    hipMemsetAsync(ws, 0, 2048, stream);
    k_wt<<<(13 * 9 * 32 * 32 + 255) / 256, 256, 0, stream>>>(ws_w, wt);
    k_compact0<<<1024, 256, 0, stream>>>(
        (const float4*)mask, (int*)(ws + idx_off[0]), (int*)(ws + coord_off[0]), cnt, caps[0]);

    {   // F1: down1 + conv0
        int downB = 1024;                       // (1024*1024/4)/256
        int convB = (caps[0] * 32 + 255) / 256; // 5632
        k_f1<<<downB + convB, 256, 0, stream>>>(
            downB,
            (const int*)(ws + idx_off[0]), (int*)(ws + idx_off[1]), (int*)(ws + coord_off[1]),
            cnt + 1, caps[1],
            x, w1, (const int*)(ws + coord_off[0]), cnt, caps[0],
            (float*)(ws + val_off[0]));
    }
    for (int i = 2; i <= 8; i++) {
        int lc = i - 1;
        int Hout = 1 << Hb[i];
        int downB = ((Hout * Hout / 4) + 255) / 256;
        if (downB < 1) downB = 1;
        int groups = (caps[lc] + 15) / 16;
        int convB = groups < 1024 ? groups : 1024;
        k_fused<<<downB + convB, 256, 0, stream>>>(
            downB,
            (const int*)(ws + idx_off[i - 1]), Hb[i - 1],
            (int*)(ws + idx_off[i]), (int*)(ws + coord_off[i]), cnt + i, Hb[i], caps[i],
            (const float*)(ws + val_off[lc - 1]), (const int*)(ws + idx_off[lc - 1]), Hb[lc - 1],
            wt + (size_t)(lc - 1) * 9 * 1024,
            (const int*)(ws + coord_off[lc]), cnt + lc, caps[lc],
            (float*)(ws + val_off[lc]), Hb[lc]);
    }

    TailArgs ta;
    for (int i = 0; i < NLVL; i++) {
        ta.idx[i] = idx_off[i]; ta.coord[i] = coord_off[i]; ta.val[i] = val_off[i];
        ta.cap[i] = caps[i]; ta.Hb[i] = Hb[i];
    }
    k_tail<<<1, 1024, 0, stream>>>(ws, ta, wt, cnt);

    PoolArgs pa;
    for (int i = 0; i < NLVL; i++) { pa.voff[i] = val_off[i]; pa.cap[i] = caps[i]; }
    k_pool<<<NLVL * 32, 256, 0, stream>>>((const char*)ws, pa, cnt, poolsum);
    k_mlp<<<1, 256, 0, stream>>>(poolsum, cnt, wm1, bm1, wm2, bm2, out);
}

// Round 3
// 520.970 us; speedup vs baseline: 1.0885x; 1.0885x over previous
//
#include <hip/hip_runtime.h>

#define NLVL 14

__device__ __forceinline__ float fma4(float4 v, float4 w, float acc) {
    acc = fmaf(v.x, w.x, acc);
    acc = fmaf(v.y, w.y, acc);
    acc = fmaf(v.z, w.z, acc);
    return fmaf(v.w, w.w, acc);
}

// exclusive prefix over a 256-thread block, one atomicAdd per block.
__device__ __forceinline__ int block_scan_base(int mycnt, int* gcnt, int& myoff) {
    __shared__ int wsum[4];
    __shared__ int base;
    int lane = threadIdx.x & 63, wid = threadIdx.x >> 6;
    int scan = mycnt;
    #pragma unroll
    for (int d = 1; d < 64; d <<= 1) {
        int tv = __shfl_up(scan, d, 64);
        if (lane >= d) scan += tv;
    }
    if (lane == 63) wsum[wid] = scan;
    __syncthreads();
    if (threadIdx.x == 0) {
        int tot = 0;
        #pragma unroll
        for (int i = 0; i < 4; i++) { int tv = wsum[i]; wsum[i] = tot; tot += tv; }
        base = tot ? atomicAdd(gcnt, tot) : 0;
    }
    __syncthreads();
    myoff = wsum[wid] + scan - mycnt;
    return base;
}

// ---- downsample level (2x2 max) + emit per-slot 3x3 neighbor j-lists ----
__device__ __forceinline__ void down_nbr(
    const int* __restrict__ idx_in, int HinB,
    int* __restrict__ idx_out, int* __restrict__ nbr_out, int* __restrict__ cnt_out,
    int HoutB, int cap_out, int bb) {
    int Hout = 1 << HoutB, Hin = 1 << HinB;
    int S = Hout * Hout;
    int S4 = (S + 3) >> 2;
    int o4 = bb * 256 + threadIdx.x;
    int e0 = o4 << 2;
    int jv[4][9];
    int pr[4] = {0, 0, 0, 0};
    #pragma unroll
    for (int k = 0; k < 4; k++)
        #pragma unroll
        for (int tap = 0; tap < 9; tap++) jv[k][tap] = -1;
    if (o4 < S4) {
        if (HoutB >= 2) {
            int r = e0 >> HoutB, c0 = e0 & (Hout - 1);
            int w[3][12];
            #pragma unroll
            for (int a = 0; a < 3; a++) {
                int rr = 2 * r + a - 1;
                bool rok = (unsigned)rr < (unsigned)Hin;
                const int* rowp = idx_in + ((size_t)(rok ? rr : 0) << HinB) + 2 * c0;
                int4 L = (rok && c0 > 0) ? *(const int4*)(rowp - 4) : make_int4(-1, -1, -1, -1);
                int4 M = rok ? *(const int4*)rowp : make_int4(-1, -1, -1, -1);
                int4 R = rok ? *(const int4*)(rowp + 4) : make_int4(-1, -1, -1, -1);
                w[a][0] = L.x; w[a][1] = L.y; w[a][2]  = L.z; w[a][3]  = L.w;
                w[a][4] = M.x; w[a][5] = M.y; w[a][6]  = M.z; w[a][7]  = M.w;
                w[a][8] = R.x; w[a][9] = R.y; w[a][10] = R.z; w[a][11] = R.w;
            }
            // col = 2*(c0+k)+b-1 -> window offset 2k+b+3 (window starts at col 2c0-4)
            #pragma unroll
            for (int k = 0; k < 4; k++) {
                #pragma unroll
                for (int a = 0; a < 3; a++)
                    #pragma unroll
                    for (int b = 0; b < 3; b++)
                        jv[k][a * 3 + b] = w[a][2 * k + b + 3];
                pr[k] = ((jv[k][4] & jv[k][5] & jv[k][7] & jv[k][8]) >= 0);
            }
        } else {   // Hout 1 or 2
            #pragma unroll
            for (int k = 0; k < 4; k++) {
                int p = e0 + k;
                if (p < S) {
                    int r = p >> HoutB, c = p & (Hout - 1);
                    #pragma unroll
                    for (int a = 0; a < 3; a++)
                        #pragma unroll
                        for (int b = 0; b < 3; b++) {
                            int rr = 2 * r + a - 1, cc = 2 * c + b - 1;
                            if ((unsigned)rr < (unsigned)Hin && (unsigned)cc < (unsigned)Hin)
                                jv[k][a * 3 + b] = idx_in[((size_t)rr << HinB) + cc];
                        }
                    pr[k] = ((jv[k][4] & jv[k][5] & jv[k][7] & jv[k][8]) >= 0);
                }
            }
        }
    }
    int mycnt = pr[0] + pr[1] + pr[2] + pr[3];
    int myoff;
    int base = block_scan_base(mycnt, cnt_out, myoff);
    int slot = base + myoff;
    int wv[4] = {-1, -1, -1, -1};
    #pragma unroll
    for (int k = 0; k < 4; k++) {
        if (pr[k]) {
            int sl = slot++;
            if (sl < cap_out) {
                wv[k] = sl;
                #pragma unroll
                for (int tap = 0; tap < 9; tap++) nbr_out[sl * 9 + tap] = jv[k][tap];
            }
        }
    }
    if (o4 < S4) {
        if (S >= 4) *(int4*)(idx_out + e0) = make_int4(wv[0], wv[1], wv[2], wv[3]);
        else {
            #pragma unroll
            for (int k = 0; k < 4; k++) if (e0 + k < S) idx_out[e0 + k] = wv[k];
        }
    }
}

// ---- conv 3x3 stride-2, 32->32, gather via precomputed nbr lists ----
// block = 16 slots; thread = (co = t>>3, ciq = t&7); weights in VGPRs.
__device__ __forceinline__ void conv_part(
    const float* __restrict__ vprev, const float* __restrict__ wlvl,
    const int* __restrict__ nbr, const int* __restrict__ cnt_c, int cap_c,
    float* __restrict__ vals_c, int bb) {
    __shared__ int s_j[144];
    int t = threadIdx.x;
    int ciq = t & 7, co = t >> 3;
    int n = *cnt_c; if (n > cap_c) n = cap_c;
    int sg0 = bb << 4;
    if (sg0 >= n) return;
    float4 wreg[9];
    #pragma unroll
    for (int tap = 0; tap < 9; tap++)
        wreg[tap] = *(const float4*)(wlvl + ((tap * 32 + co) << 5) + (ciq << 2));
    if (t < 144) {
        int gi = sg0 * 9 + t;
        s_j[t] = (gi < n * 9) ? nbr[gi] : -1;
    }
    __syncthreads();
    #pragma unroll 2
    for (int g = 0; g < 16; g += 2) {
        int s0 = sg0 + g, s1 = s0 + 1;
        float a0 = 0.f, a1 = 0.f;
        #pragma unroll
        for (int tap = 0; tap < 9; tap++) {
            int j0 = s_j[g * 9 + tap];
            if (j0 >= 0)
                a0 = fma4(*(const float4*)(vprev + ((size_t)j0 << 5) + (ciq << 2)), wreg[tap], a0);
            int j1 = s_j[g * 9 + 9 + tap];
            if (j1 >= 0)
                a1 = fma4(*(const float4*)(vprev + ((size_t)j1 << 5) + (ciq << 2)), wreg[tap], a1);
        }
        a0 += __shfl_xor(a0, 1); a0 += __shfl_xor(a0, 2); a0 += __shfl_xor(a0, 4);
        a1 += __shfl_xor(a1, 1); a1 += __shfl_xor(a1, 2); a1 += __shfl_xor(a1, 4);
        if (ciq == 0) {
            if (s0 < n) vals_c[((size_t)s0 << 5) + co] = fmaxf(a0, 0.f);
            if (s1 < n) vals_c[((size_t)s1 << 5) + co] = fmaxf(a1, 0.f);
        }
    }
}

// F0 = level-0 mask compaction (blocks 0..1023) + weight transpose (blocks 1024..)
__global__ __launch_bounds__(256) void k_f0(
    const float4* __restrict__ mask4, int* __restrict__ idxmap,
    int* __restrict__ coords, int* __restrict__ cnt, int cap,
    const float* __restrict__ w, float* __restrict__ wt) {
    if (blockIdx.x >= 1024) {
        int t = (int)(blockIdx.x - 1024) * 256 + threadIdx.x;
        if (t < 13 * 9 * 32 * 32) {
            int ci = t & 31, co = (t >> 5) & 31, tp = t >> 10;
            wt[(tp << 10) + (co << 5) + ci] = w[(tp << 10) + (ci << 5) + co];
        }
        return;
    }
    int t = threadIdx.x;
    int g0 = blockIdx.x * 1024 + t;
    float4 m[4];
    #pragma unroll
    for (int j = 0; j < 4; j++) m[j] = mask4[g0 + j * 256];
    int pr[16];
    int mycnt = 0;
    #pragma unroll
    for (int j = 0; j < 4; j++) {
        pr[4 * j + 0] = m[j].x > 0.5f;
        pr[4 * j + 1] = m[j].y > 0.5f;
        pr[4 * j + 2] = m[j].z > 0.5f;
        pr[4 * j + 3] = m[j].w > 0.5f;
        mycnt += pr[4 * j] + pr[4 * j + 1] + pr[4 * j + 2] + pr[4 * j + 3];
    }
    int myoff;
    int base = block_scan_base(mycnt, cnt, myoff);
    int slot = base + myoff;
    #pragma unroll
    for (int j = 0; j < 4; j++) {
        int e0 = (g0 + j * 256) << 2;
        int wv[4];
        #pragma unroll
        for (int k = 0; k < 4; k++) {
            wv[k] = -1;
            if (pr[4 * j + k]) {
                int sl = slot++;
                if (sl < cap) { wv[k] = sl; coords[sl] = e0 + k; }
            }
        }
        *(int4*)(idxmap + e0) = make_int4(wv[0], wv[1], wv[2], wv[3]);
    }
}

// F1 = down1(+nbr1) + conv0 (5x5, cin=1, dense-x gather) + wm1/wm2 cache warm
__global__ __launch_bounds__(256) void k_f1(
    const int* __restrict__ idx0, int* __restrict__ idx1, int* __restrict__ nbr1,
    int* __restrict__ cnt1, int cap1,
    const float* __restrict__ x, const float* __restrict__ w1,
    const int* __restrict__ coords0, const int* __restrict__ cnt0, int cap0,
    float* __restrict__ vals0,
    const float* __restrict__ wm1, const float* __restrict__ wm2, float* __restrict__ dummy) {
    if (blockIdx.x < 1024) {
        down_nbr(idx0, 11, idx1, nbr1, cnt1, 10, cap1, blockIdx.x);
        return;
    }
    if (blockIdx.x >= 6656) {   // 24 warm blocks: touch wm1/wm2 lines into L2/L3
        int t = (int)(blockIdx.x - 6656) * 256 + threadIdx.x;
        const float4* a = (const float4*)wm1;
        const float4* b = (const float4*)wm2;
        float acc = 0.f;
        for (int i = t; i < 28672; i += 6144) { float4 v = a[i]; acc += v.x + v.y + v.z + v.w; }
        for (int i = t; i < 8192; i += 6144)  { float4 v = b[i]; acc += v.x + v.y + v.z + v.w; }
        if (acc == 1234.56789f) dummy[0] = acc;   // never true; defeats DCE
        return;
    }
    int tt = (int)(blockIdx.x - 1024) * 256 + threadIdx.x;
    int s = tt >> 5, ch = tt & 31;
    int n = *cnt0; if (n > cap0) n = cap0;
    if (s >= n) return;
    int p = coords0[s];
    int r = p >> 11, c = p & 2047;
    float acc = 0.f;
    #pragma unroll
    for (int a = 0; a < 5; a++) {
        int rr = r + a - 2;
        if ((unsigned)rr >= 2048u) continue;
        #pragma unroll
        for (int b = 0; b < 5; b++) {
            int cc = c + b - 2;
            if ((unsigned)cc >= 2048u) continue;
            acc = fmaf(x[(rr << 11) + cc], w1[(a * 5 + b) * 32 + ch], acc);
        }
    }
    vals0[((size_t)s << 5) + ch] = fmaxf(acc, 0.f);
}

// F_i (i=2..13): down_i (+nbr_i) fused with conv_{i-1}
__global__ __launch_bounds__(256) void k_flevel(
    int downB,
    const int* __restrict__ idx_in, int HinB,
    int* __restrict__ idx_out, int* __restrict__ nbr_out, int* __restrict__ cnt_out,
    int HoutB, int cap_out,
    const float* __restrict__ vprev, const float* __restrict__ wlvl,
    const int* __restrict__ nbr_c, const int* __restrict__ cnt_c, int cap_c,
    float* __restrict__ vals_c) {
    if ((int)blockIdx.x < downB) {
        down_nbr(idx_in, HinB, idx_out, nbr_out, cnt_out, HoutB, cap_out, blockIdx.x);
        return;
    }
    conv_part(vprev, wlvl, nbr_c, cnt_c, cap_c, vals_c, blockIdx.x - downB);
}

struct PoolArgs {
    unsigned long long voff[NLVL];
    int cap[NLVL];
};

// F14 = conv13 (block 0) + pooling for levels 0..12 (blocks 1..416)
__global__ __launch_bounds__(256) void k_f14(
    const char* __restrict__ wsb, PoolArgs pa,
    const int* __restrict__ cnt, float* __restrict__ poolsum,
    const float* __restrict__ vals12, const float* __restrict__ wt12,
    const int* __restrict__ nbr13, const int* __restrict__ cnt13p,
    float* __restrict__ vals13) {
    if (blockIdx.x == 0) {
        conv_part(vals12, wt12, nbr13, cnt13p, 1, vals13, 0);
        return;
    }
    __shared__ float red[256];
    int b = blockIdx.x - 1;
    int lvl = b >> 5, chunk = b & 31;      // lvl 0..12
    const float* vals = (const float*)(wsb + pa.voff[lvl]);
    int n = cnt[lvl]; if (n > pa.cap[lvl]) n = pa.cap[lvl];
    int ch = threadIdx.x & 31;
    int s0 = chunk * 8 + (threadIdx.x >> 5);
    float acc = 0.f;
    for (int s = s0; s < n; s += 256)
        acc += vals[((size_t)s << 5) + ch];
    red[threadIdx.x] = acc;
    __syncthreads();
    if (threadIdx.x < 32) {
        float tot = 0.f;
        #pragma unroll
        for (int g = 0; g < 8; g++) tot += red[threadIdx.x + 32 * g];
        atomicAdd(&poolsum[lvl * 32 + threadIdx.x], tot);
    }
}

// MLP: feat(448) -> relu(@wm1+bm1)(256) -> @wm2+bm2 (128). 1024 threads, k-split.
__global__ __launch_bounds__(1024) void k_mlp(
    const float* __restrict__ poolsum, const int* __restrict__ cnt,
    const float* __restrict__ vals13,
    const float* __restrict__ wm1, const float* __restrict__ bm1,
    const float* __restrict__ wm2, const float* __restrict__ bm2,
    float* __restrict__ out) {
    __shared__ float feat[448];
    __shared__ float h[256];
    __shared__ float part[1024];
    int tid = threadIdx.x;
    for (int k = tid; k < 416; k += 1024) {
        float c = (float)cnt[k >> 5]; if (c < 1.f) c = 1.f;
        feat[k] = poolsum[k] / c;
    }
    if (tid < 32) {
        int n13 = cnt[13];
        float c = (float)n13; if (c < 1.f) c = 1.f;
        feat[416 + tid] = (n13 > 0) ? vals13[tid] / c : 0.f;
    }
    __syncthreads();
    int j = tid & 255, chunk = tid >> 8;     // 4 k-chunks of 112
    float acc = (chunk == 0) ? bm1[j] : 0.f;
    int k0 = chunk * 112;
    #pragma unroll 8
    for (int k = k0; k < k0 + 112; k++) acc = fmaf(feat[k], wm1[k * 256 + j], acc);
    part[tid] = acc;
    __syncthreads();
    if (tid < 256)
        h[tid] = fmaxf(part[tid] + part[tid + 256] + part[tid + 512] + part[tid + 768], 0.f);
    __syncthreads();
    int j2 = tid & 127, c2 = tid >> 7;       // 8 k-chunks of 32
    float a2 = (c2 == 0) ? bm2[j2] : 0.f;
    int kk0 = c2 * 32;
    #pragma unroll 8
    for (int k = kk0; k < kk0 + 32; k++) a2 = fmaf(h[k], wm2[k * 128 + j2], a2);
    part[tid] = a2;
    __syncthreads();
    if (tid < 128) {
        float s = 0.f;
        #pragma unroll
        for (int c = 0; c < 8; c++) s += part[tid + 128 * c];
        out[tid] = s;
    }
}

extern "C" void kernel_launch(void* const* d_in, const int* in_sizes, int n_in,
                              void* d_out, int out_size, void* d_ws, size_t ws_size,
                              hipStream_t stream) {
    const float* x    = (const float*)d_in[0];
    const float* mask = (const float*)d_in[1];
    const float* w1   = (const float*)d_in[2];
    const float* ws_w = (const float*)d_in[3];
    const float* wm1  = (const float*)d_in[4];
    const float* bm1  = (const float*)d_in[5];
    const float* wm2  = (const float*)d_in[6];
    const float* bm2  = (const float*)d_in[7];
    float* out = (float*)d_out;
    char* ws = (char*)d_ws;

    static const int Hb[NLVL]   = {11, 10, 9, 8, 7, 6, 5, 4, 3, 2, 1, 0, 0, 0};
    static const int caps[NLVL] = {45056, 43008, 43008, 34816, 16384, 4096,
                                   1024, 256, 64, 16, 4, 1, 1, 1};

    // ws layout: cnt[16] @0, poolsum[448] @64, dummy @1856, wt @2048
    size_t wt_off = 2048;
    size_t off = wt_off + (size_t)13 * 9 * 1024 * 4;          // 481280
    size_t coord0_off = off; off += (size_t)caps[0] * 4; off = (off + 255) & ~(size_t)255;
    size_t idx_off[NLVL], nbr_off[NLVL], val_off[NLVL];
    for (int l = 0; l < NLVL; l++) {
        size_t S = (size_t)(1 << Hb[l]) * (1 << Hb[l]);
        size_t sb = S * 4; if (sb < 16) sb = 16;
        idx_off[l] = off; off += sb;                       off = (off + 255) & ~(size_t)255;
        if (l >= 1) { nbr_off[l] = off; off += (size_t)caps[l] * 36; off = (off + 255) & ~(size_t)255; }
        val_off[l] = off; off += (size_t)caps[l] * 128;    off = (off + 255) & ~(size_t)255;
    }

    int* cnt = (int*)ws;
    float* poolsum = (float*)(ws + 64);
    float* dummy = (float*)(ws + 1856);
    float* wt = (float*)(ws + wt_off);

    hipMemsetAsync(ws, 0, 2048, stream);

    k_f0<<<1024 + 468, 256, 0, stream>>>(
        (const float4*)mask, (int*)(ws + idx_off[0]), (int*)(ws + coord0_off),
        cnt, caps[0], ws_w, wt);

    k_f1<<<6680, 256, 0, stream>>>(
        (const int*)(ws + idx_off[0]), (int*)(ws + idx_off[1]), (int*)(ws + nbr_off[1]),
        cnt + 1, caps[1],
        x, w1, (const int*)(ws + coord0_off), cnt, caps[0],
        (float*)(ws + val_off[0]), wm1, wm2, dummy);

    for (int i = 2; i < NLVL; i++) {
        int S = (1 << Hb[i]) * (1 << Hb[i]);
        int S4 = (S + 3) >> 2;
        int downB = (S4 + 255) / 256; if (downB < 1) downB = 1;
        int convB = (caps[i - 1] + 15) / 16;
        k_flevel<<<downB + convB, 256, 0, stream>>>(
            downB,
            (const int*)(ws + idx_off[i - 1]), Hb[i - 1],
            (int*)(ws + idx_off[i]), (int*)(ws + nbr_off[i]), cnt + i, Hb[i], caps[i],
            (const float*)(ws + val_off[i - 2]), wt + (size_t)(i - 2) * 9216,
            (const int*)(ws + nbr_off[i - 1]), cnt + (i - 1), caps[i - 1],
            (float*)(ws + val_off[i - 1]));
    }

    PoolArgs pa;
    for (int l = 0; l < NLVL; l++) { pa.voff[l] = val_off[l]; pa.cap[l] = caps[l]; }
    k_f14<<<1 + 13 * 32, 256, 0, stream>>>(
        (const char*)ws, pa, cnt, poolsum,
        (const float*)(ws + val_off[12]), wt + (size_t)12 * 9216,
        (const int*)(ws + nbr_off[13]), cnt + 13,
        (float*)(ws + val_off[13]));

    k_mlp<<<1, 1024, 0, stream>>>(poolsum, cnt, (const float*)(ws + val_off[13]),
                                  wm1, bm1, wm2, bm2, out);
}

// Round 5
// 371.621 us; speedup vs baseline: 1.5260x; 1.4019x over previous
//
#include <hip/hip_runtime.h>

#define NLVL 14
#define NSHARD 16

__device__ __forceinline__ float fma4(float4 v, float4 w, float acc) {
    acc = fmaf(v.x, w.x, acc);
    acc = fmaf(v.y, w.y, acc);
    acc = fmaf(v.z, w.z, acc);
    return fmaf(v.w, w.w, acc);
}

// exclusive prefix over a 256-thread block, one atomicAdd per block.
__device__ __forceinline__ int block_scan_base(int mycnt, int* gcnt, int& myoff) {
    __shared__ int wsum[4];
    __shared__ int base;
    int lane = threadIdx.x & 63, wid = threadIdx.x >> 6;
    int scan = mycnt;
    #pragma unroll
    for (int d = 1; d < 64; d <<= 1) {
        int tv = __shfl_up(scan, d, 64);
        if (lane >= d) scan += tv;
    }
    if (lane == 63) wsum[wid] = scan;
    __syncthreads();
    if (threadIdx.x == 0) {
        int tot = 0;
        #pragma unroll
        for (int i = 0; i < 4; i++) { int tv = wsum[i]; wsum[i] = tot; tot += tv; }
        base = tot ? atomicAdd(gcnt, tot) : 0;
    }
    __syncthreads();
    myoff = wsum[wid] + scan - mycnt;
    return base;
}

// ---- level-0 mask compaction tile (validated R3) ----
__device__ void compact0_tile(const float4* __restrict__ mask4, int* __restrict__ idxmap,
                              int* __restrict__ coords, int* __restrict__ cnt, int cap, int tile) {
    int t = threadIdx.x;
    int g0 = tile * 1024 + t;
    float4 m[4];
    #pragma unroll
    for (int j = 0; j < 4; j++) m[j] = mask4[g0 + j * 256];
    int pr[16];
    int mycnt = 0;
    #pragma unroll
    for (int j = 0; j < 4; j++) {
        pr[4 * j + 0] = m[j].x > 0.5f;
        pr[4 * j + 1] = m[j].y > 0.5f;
        pr[4 * j + 2] = m[j].z > 0.5f;
        pr[4 * j + 3] = m[j].w > 0.5f;
        mycnt += pr[4 * j] + pr[4 * j + 1] + pr[4 * j + 2] + pr[4 * j + 3];
    }
    int myoff;
    int base = block_scan_base(mycnt, cnt, myoff);
    int slot = base + myoff;
    #pragma unroll
    for (int j = 0; j < 4; j++) {
        int e0 = (g0 + j * 256) << 2;
        int wv[4];
        #pragma unroll
        for (int k = 0; k < 4; k++) {
            wv[k] = -1;
            if (pr[4 * j + k]) {
                int sl = slot++;
                if (sl < cap) { wv[k] = sl; coords[sl] = e0 + k; }
            }
        }
        *(int4*)(idxmap + e0) = make_int4(wv[0], wv[1], wv[2], wv[3]);
    }
}

// ---- downsample + neighbor-list tile (validated R3) ----
__device__ void down_nbr(const int* __restrict__ idx_in, int HinB,
                         int* __restrict__ idx_out, int* __restrict__ nbr_out,
                         int* __restrict__ cnt_out, int HoutB, int cap_out, int bb) {
    int Hout = 1 << HoutB, Hin = 1 << HinB;
    int S = Hout * Hout;
    int S4 = (S + 3) >> 2;
    int o4 = bb * 256 + threadIdx.x;
    int e0 = o4 << 2;
    int jv[4][9];
    int pr[4] = {0, 0, 0, 0};
    #pragma unroll
    for (int k = 0; k < 4; k++)
        #pragma unroll
        for (int tap = 0; tap < 9; tap++) jv[k][tap] = -1;
    if (o4 < S4) {
        if (HoutB >= 2) {
            int r = e0 >> HoutB, c0 = e0 & (Hout - 1);
            int w[3][12];
            #pragma unroll
            for (int a = 0; a < 3; a++) {
                int rr = 2 * r + a - 1;
                bool rok = (unsigned)rr < (unsigned)Hin;
                const int* rowp = idx_in + ((size_t)(rok ? rr : 0) << HinB) + 2 * c0;
                int4 L = (rok && c0 > 0) ? *(const int4*)(rowp - 4) : make_int4(-1, -1, -1, -1);
                int4 M = rok ? *(const int4*)rowp : make_int4(-1, -1, -1, -1);
                int4 R = rok ? *(const int4*)(rowp + 4) : make_int4(-1, -1, -1, -1);
                w[a][0] = L.x; w[a][1] = L.y; w[a][2]  = L.z; w[a][3]  = L.w;
                w[a][4] = M.x; w[a][5] = M.y; w[a][6]  = M.z; w[a][7]  = M.w;
                w[a][8] = R.x; w[a][9] = R.y; w[a][10] = R.z; w[a][11] = R.w;
            }
            #pragma unroll
            for (int k = 0; k < 4; k++) {
                #pragma unroll
                for (int a = 0; a < 3; a++)
                    #pragma unroll
                    for (int b = 0; b < 3; b++)
                        jv[k][a * 3 + b] = w[a][2 * k + b + 3];
                pr[k] = ((jv[k][4] & jv[k][5] & jv[k][7] & jv[k][8]) >= 0);
            }
        } else {
            #pragma unroll
            for (int k = 0; k < 4; k++) {
                int p = e0 + k;
                if (p < S) {
                    int r = p >> HoutB, c = p & (Hout - 1);
                    #pragma unroll
                    for (int a = 0; a < 3; a++)
                        #pragma unroll
                        for (int b = 0; b < 3; b++) {
                            int rr = 2 * r + a - 1, cc = 2 * c + b - 1;
                            if ((unsigned)rr < (unsigned)Hin && (unsigned)cc < (unsigned)Hin)
                                jv[k][a * 3 + b] = idx_in[((size_t)rr << HinB) + cc];
                        }
                    pr[k] = ((jv[k][4] & jv[k][5] & jv[k][7] & jv[k][8]) >= 0);
                }
            }
        }
    }
    int mycnt = pr[0] + pr[1] + pr[2] + pr[3];
    int myoff;
    int base = block_scan_base(mycnt, cnt_out, myoff);
    int slot = base + myoff;
    int wv[4] = {-1, -1, -1, -1};
    #pragma unroll
    for (int k = 0; k < 4; k++) {
        if (pr[k]) {
            int sl = slot++;
            if (sl < cap_out) {
                wv[k] = sl;
                #pragma unroll
                for (int tap = 0; tap < 9; tap++) nbr_out[sl * 9 + tap] = jv[k][tap];
            }
        }
    }
    if (o4 < S4) {
        if (S >= 4) *(int4*)(idx_out + e0) = make_int4(wv[0], wv[1], wv[2], wv[3]);
        else {
            #pragma unroll
            for (int k = 0; k < 4; k++) if (e0 + k < S) idx_out[e0 + k] = wv[k];
        }
    }
}

// ---- conv 3x3 s2 32->32: batched in-flight tap loads + folded pool ----
__device__ void conv_bs(const float* __restrict__ vprev, const float* __restrict__ wlvl,
                        const int* __restrict__ nbr, int n,
                        float* __restrict__ vals, float* __restrict__ poolp,
                        int b0, int nbk, int shard) {
    __shared__ int s_j[144];
    int t = threadIdx.x;
    int ciq = t & 7, co = t >> 3;
    float4 wreg[9];
    #pragma unroll
    for (int tap = 0; tap < 9; tap++)
        wreg[tap] = *(const float4*)(wlvl + ((tap * 32 + co) << 5) + (ciq << 2));
    float psum = 0.f;
    int ngr = (n + 15) >> 4;
    const float4 z4 = make_float4(0.f, 0.f, 0.f, 0.f);
    for (int grp = b0; grp < ngr; grp += nbk) {
        __syncthreads();
        if (t < 144) {
            int gi = grp * 144 + t;
            s_j[t] = (gi < n * 9) ? nbr[gi] : -1;
        }
        __syncthreads();
        #pragma unroll 2
        for (int g = 0; g < 16; g += 2) {
            int s0 = (grp << 4) + g, s1 = s0 + 1;
            float4 v0[9], v1[9];
            int j0r[9], j1r[9];
            #pragma unroll
            for (int tap = 0; tap < 9; tap++) {
                int j0 = s_j[g * 9 + tap];
                int j1 = s_j[g * 9 + 9 + tap];
                j0r[tap] = j0; j1r[tap] = j1;
                int jc0 = j0 < 0 ? 0 : j0;
                int jc1 = j1 < 0 ? 0 : j1;
                v0[tap] = *(const float4*)(vprev + ((size_t)jc0 << 5) + (ciq << 2));
                v1[tap] = *(const float4*)(vprev + ((size_t)jc1 << 5) + (ciq << 2));
            }
            float a0 = 0.f, a1 = 0.f;
            #pragma unroll
            for (int tap = 0; tap < 9; tap++) {
                float4 u0 = (j0r[tap] >= 0) ? v0[tap] : z4;
                float4 u1 = (j1r[tap] >= 0) ? v1[tap] : z4;
                a0 = fma4(u0, wreg[tap], a0);
                a1 = fma4(u1, wreg[tap], a1);
            }
            a0 += __shfl_xor(a0, 1); a0 += __shfl_xor(a0, 2); a0 += __shfl_xor(a0, 4);
            a1 += __shfl_xor(a1, 1); a1 += __shfl_xor(a1, 2); a1 += __shfl_xor(a1, 4);
            if (ciq == 0) {
                if (s0 < n) { float r0 = fmaxf(a0, 0.f); vals[((size_t)s0 << 5) + co] = r0; psum += r0; }
                if (s1 < n) { float r1 = fmaxf(a1, 0.f); vals[((size_t)s1 << 5) + co] = r1; psum += r1; }
            }
        }
    }
    if (ciq == 0 && psum != 0.f) atomicAdd(&poolp[shard * 448 + co], psum);
}

// ---- conv0 (5x5, cin=1): LDS-staged windows, folded pool ----
__device__ void conv0_bs(const float* __restrict__ x, const float* __restrict__ w1,
                         const int* __restrict__ coords0, int n,
                         float* __restrict__ vals0, float* __restrict__ poolp,
                         int b0, int nbk, int shard) {
    __shared__ float lw[800];
    __shared__ float lx[8][28];
    __shared__ float red[256];
    int t = threadIdx.x;
    for (int i = t; i < 800; i += 256) lw[i] = w1[i];
    int sl = t >> 5, ch = t & 31;
    float psum = 0.f;
    int ngr = (n + 7) >> 3;
    for (int grp = b0; grp < ngr; grp += nbk) {
        __syncthreads();
        if (t < 200) {
            int slot = t / 25, tap = t - slot * 25;
            int s = (grp << 3) + slot;
            float v = 0.f;
            if (s < n) {
                int p = coords0[s];
                int r = p >> 11, c = p & 2047;
                int a = tap / 5, b = tap - a * 5;
                int rr = r + a - 2, cc = c + b - 2;
                if ((unsigned)rr < 2048u && (unsigned)cc < 2048u)
                    v = x[(rr << 11) + cc];
            }
            lx[slot][tap] = v;
        }
        __syncthreads();
        int s = (grp << 3) + sl;
        float acc = 0.f;
        #pragma unroll
        for (int tap = 0; tap < 25; tap++)
            acc = fmaf(lx[sl][tap], lw[tap * 32 + ch], acc);
        if (s < n) {
            float r0 = fmaxf(acc, 0.f);
            vals0[((size_t)s << 5) + ch] = r0;
            psum += r0;
        }
    }
    __syncthreads();
    red[t] = psum;
    __syncthreads();
    if (t < 32) {
        float tot = 0.f;
        #pragma unroll
        for (int q = 0; q < 8; q++) tot += red[t + 32 * q];
        if (tot != 0.f) atomicAdd(&poolp[shard * 448 + t], tot);
    }
}

// F0 = level-0 compaction (blocks 0..1023) + weight transpose (blocks 1024..)
__global__ __launch_bounds__(256) void k_f0(
    const float4* __restrict__ mask4, int* __restrict__ idxmap,
    int* __restrict__ coords, int* __restrict__ cnt, int cap,
    const float* __restrict__ w, float* __restrict__ wt) {
    if (blockIdx.x >= 1024) {
        int t = (int)(blockIdx.x - 1024) * 256 + threadIdx.x;
        if (t < 13 * 9 * 32 * 32) {
            int ci = t & 31, co = (t >> 5) & 31, tp = t >> 10;
            wt[(tp << 10) + (co << 5) + ci] = w[(tp << 10) + (ci << 5) + co];
        }
        return;
    }
    compact0_tile(mask4, idxmap, coords, cnt, cap, blockIdx.x);
}

// F1 = down1+nbr1 (0..1023) + conv0 (1024..3071) + wm warm (3072..3095)
__global__ __launch_bounds__(256) void k_f1(
    const int* __restrict__ idx0, int* __restrict__ idx1, int* __restrict__ nbr1,
    int* __restrict__ cnt1, int cap1,
    const float* __restrict__ x, const float* __restrict__ w1,
    const int* __restrict__ coords0, const int* __restrict__ cnt0, int cap0,
    float* __restrict__ vals0, float* __restrict__ poolp,
    const float* __restrict__ wm1, const float* __restrict__ wm2, float* __restrict__ dummy) {
    if (blockIdx.x < 1024) {
        down_nbr(idx0, 11, idx1, nbr1, cnt1, 10, cap1, blockIdx.x);
        return;
    }
    if (blockIdx.x >= 3072) {
        int t = (int)(blockIdx.x - 3072) * 256 + threadIdx.x;
        const float4* a = (const float4*)wm1;
        const float4* b = (const float4*)wm2;
        float acc = 0.f;
        for (int i = t; i < 28672; i += 6144) { float4 v = a[i]; acc += v.x + v.y + v.z + v.w; }
        for (int i = t; i < 8192; i += 6144)  { float4 v = b[i]; acc += v.x + v.y + v.z + v.w; }
        if (acc == 1234.56789f) dummy[0] = acc;
        return;
    }
    int n = *cnt0; if (n > cap0) n = cap0;
    conv0_bs(x, w1, coords0, n, vals0, poolp, blockIdx.x - 1024, 2048, blockIdx.x & (NSHARD - 1));
}

// F_i (i=2..10): down_i (+nbr_i) fused with conv_{i-1} (+pool_{i-1})
__global__ __launch_bounds__(256) void k_flevel(
    int downB,
    const int* __restrict__ idx_in, int HinB,
    int* __restrict__ idx_out, int* __restrict__ nbr_out, int* __restrict__ cnt_out,
    int HoutB, int cap_out,
    const float* __restrict__ vprev, const float* __restrict__ wlvl,
    const int* __restrict__ nbr_c, const int* __restrict__ cnt_c, int cap_c,
    float* __restrict__ vals_c, float* __restrict__ poolp) {
    if ((int)blockIdx.x < downB) {
        down_nbr(idx_in, HinB, idx_out, nbr_out, cnt_out, HoutB, cap_out, blockIdx.x);
        return;
    }
    int n = *cnt_c; if (n > cap_c) n = cap_c;
    conv_bs(vprev, wlvl, nbr_c, n, vals_c, poolp,
            blockIdx.x - downB, gridDim.x - downB, blockIdx.x & (NSHARD - 1));
}

// TAIL: conv10..conv13 (<=4 slots) + feat assembly + MLP, one 1024-thread block.
__global__ __launch_bounds__(1024) void k_tail(
    const int* __restrict__ cnt, const float* __restrict__ poolsh,
    const float* __restrict__ vals9, const int* __restrict__ nbr10,
    const int* __restrict__ idx10, const float* __restrict__ wt,
    const float* __restrict__ wm1, const float* __restrict__ bm1,
    const float* __restrict__ wm2, const float* __restrict__ bm2,
    float* __restrict__ out) {
    __shared__ float v10[128], v11[32], v12[32], v13[32];
    __shared__ float feat[448], h[256], part[1024];
    __shared__ int s_i10[4], s_n10;
    int t = threadIdx.x;
    int ciq = t & 7, co = (t >> 3) & 31, s = t >> 8;
    if (t == 0) s_n10 = cnt[10];
    if (t < 4) s_i10[t] = idx10[t];
    __syncthreads();
    int n10 = s_n10; if (n10 > 4) n10 = 4;
    const float4 z4 = make_float4(0.f, 0.f, 0.f, 0.f);
    // conv10: 4 slot-groups x 256 threads
    {
        const float* wl = wt + (size_t)9 * 9216;
        float4 wreg[9];
        #pragma unroll
        for (int tap = 0; tap < 9; tap++)
            wreg[tap] = *(const float4*)(wl + ((tap * 32 + co) << 5) + (ciq << 2));
        float a0 = 0.f;
        bool live = s < n10;
        #pragma unroll
        for (int tap = 0; tap < 9; tap++) {
            int j = live ? nbr10[s * 9 + tap] : -1;
            int jc = j < 0 ? 0 : j;
            float4 v = *(const float4*)(vals9 + ((size_t)jc << 5) + (ciq << 2));
            a0 = fma4(j >= 0 ? v : z4, wreg[tap], a0);
        }
        a0 += __shfl_xor(a0, 1); a0 += __shfl_xor(a0, 2); a0 += __shfl_xor(a0, 4);
        if (ciq == 0 && live) v10[s * 32 + co] = fmaxf(a0, 0.f);
    }
    __syncthreads();
    // down11 neighbor map (level-10 H=2 -> level-11 H=1): taps 4,5,7,8 map to i10
    int i10[4] = {s_i10[0], s_i10[1], s_i10[2], s_i10[3]};
    int nbr11[9];
    #pragma unroll
    for (int tap = 0; tap < 9; tap++) {
        int a = tap / 3, b = tap - a * 3;
        int rr = a - 1, cc = b - 1;
        nbr11[tap] = ((unsigned)rr < 2u && (unsigned)cc < 2u) ? i10[rr * 2 + cc] : -1;
    }
    int n11 = ((nbr11[4] & nbr11[5] & nbr11[7] & nbr11[8]) >= 0) ? 1 : 0;
    if (s == 0) {   // conv11 from LDS v10
        const float* wl = wt + (size_t)10 * 9216;
        float a0 = 0.f;
        #pragma unroll
        for (int tap = 0; tap < 9; tap++) {
            int j = nbr11[tap];
            if (j >= 0) {
                float4 wv = *(const float4*)(wl + ((tap * 32 + co) << 5) + (ciq << 2));
                a0 = fma4(*(const float4*)(&v10[(j << 5) + (ciq << 2)]), wv, a0);
            }
        }
        a0 += __shfl_xor(a0, 1); a0 += __shfl_xor(a0, 2); a0 += __shfl_xor(a0, 4);
        if (ciq == 0) v11[co] = n11 ? fmaxf(a0, 0.f) : 0.f;
    }
    __syncthreads();
    if (s == 0) {   // conv12: H=1 -> center tap only, live iff n11
        const float* wl = wt + (size_t)11 * 9216;
        float4 wv = *(const float4*)(wl + ((4 * 32 + co) << 5) + (ciq << 2));
        float a0 = n11 ? fma4(*(const float4*)(&v11[ciq << 2]), wv, 0.f) : 0.f;
        a0 += __shfl_xor(a0, 1); a0 += __shfl_xor(a0, 2); a0 += __shfl_xor(a0, 4);
        if (ciq == 0) v12[co] = n11 ? fmaxf(a0, 0.f) : 0.f;
    }
    __syncthreads();
    if (s == 0) {   // conv13
        const float* wl = wt + (size_t)12 * 9216;
        float4 wv = *(const float4*)(wl + ((4 * 32 + co) << 5) + (ciq << 2));
        float a0 = n11 ? fma4(*(const float4*)(&v12[ciq << 2]), wv, 0.f) : 0.f;
        a0 += __shfl_xor(a0, 1); a0 += __shfl_xor(a0, 2); a0 += __shfl_xor(a0, 4);
        if (ciq == 0) v13[co] = n11 ? fmaxf(a0, 0.f) : 0.f;
    }
    __syncthreads();
    // feat assembly
    if (t < 320) {
        float sum = 0.f;
        #pragma unroll
        for (int sh = 0; sh < NSHARD; sh++) sum += poolsh[sh * 448 + t];
        float c = (float)cnt[t >> 5]; if (c < 1.f) c = 1.f;
        feat[t] = sum / c;
    }
    if (t < 32) {
        float s10 = 0.f;
        for (int q = 0; q < n10; q++) s10 += v10[q * 32 + t];
        float c10 = (float)n10; if (c10 < 1.f) c10 = 1.f;
        feat[320 + t] = s10 / c10;
        feat[352 + t] = n11 ? v11[t] : 0.f;
        feat[384 + t] = n11 ? v12[t] : 0.f;
        feat[416 + t] = n11 ? v13[t] : 0.f;
    }
    __syncthreads();
    // MLP stage 1: 448 -> 256 (4 k-chunks of 112)
    {
        int j = t & 255, chunk = t >> 8;
        float acc = (chunk == 0) ? bm1[j] : 0.f;
        int k0 = chunk * 112;
        #pragma unroll 8
        for (int k = k0; k < k0 + 112; k++) acc = fmaf(feat[k], wm1[k * 256 + j], acc);
        part[t] = acc;
    }
    __syncthreads();
    if (t < 256)
        h[t] = fmaxf(part[t] + part[t + 256] + part[t + 512] + part[t + 768], 0.f);
    __syncthreads();
    // MLP stage 2: 256 -> 128 (8 k-chunks of 32)
    {
        int j2 = t & 127, c2 = t >> 7;
        float a2 = (c2 == 0) ? bm2[j2] : 0.f;
        int kk0 = c2 * 32;
        #pragma unroll 8
        for (int k = kk0; k < kk0 + 32; k++) a2 = fmaf(h[k], wm2[k * 128 + j2], a2);
        part[t] = a2;
    }
    __syncthreads();
    if (t < 128) {
        float sum = 0.f;
        #pragma unroll
        for (int c = 0; c < 8; c++) sum += part[t + 128 * c];
        out[t] = sum;
    }
}

extern "C" void kernel_launch(void* const* d_in, const int* in_sizes, int n_in,
                              void* d_out, int out_size, void* d_ws, size_t ws_size,
                              hipStream_t stream) {
    const float* x    = (const float*)d_in[0];
    const float* mask = (const float*)d_in[1];
    const float* w1   = (const float*)d_in[2];
    const float* wsrc = (const float*)d_in[3];
    const float* wm1  = (const float*)d_in[4];
    const float* bm1  = (const float*)d_in[5];
    const float* wm2  = (const float*)d_in[6];
    const float* bm2  = (const float*)d_in[7];
    float* out = (float*)d_out;
    char* ws = (char*)d_ws;

    static const int Hb[NLVL]   = {11, 10, 9, 8, 7, 6, 5, 4, 3, 2, 1, 0, 0, 0};
    static const int caps[NLVL] = {45056, 43008, 43008, 34816, 16384, 4096,
                                   1024, 256, 64, 16, 4, 1, 1, 1};

    // ws layout: cnt[16]@0, dummy@128, pool shards@256 (16*448 f32 = 28672B), wt@32768
    size_t pool_off = 256;
    size_t wt_off = 32768;
    size_t off = wt_off + (size_t)13 * 9 * 1024 * 4;          // 512000
    off = (off + 255) & ~(size_t)255;
    size_t coord0_off = off; off += (size_t)caps[0] * 4; off = (off + 255) & ~(size_t)255;
    size_t idx_off[NLVL], nbr_off[NLVL], val_off[NLVL];
    for (int l = 0; l < NLVL; l++) {
        size_t S = (size_t)(1 << Hb[l]) * (1 << Hb[l]);
        size_t sb = S * 4; if (sb < 16) sb = 16;
        idx_off[l] = off; off += sb; off = (off + 255) & ~(size_t)255;
        if (l >= 1) { nbr_off[l] = off; off += (size_t)caps[l] * 36; off = (off + 255) & ~(size_t)255; }
        else nbr_off[l] = 0;
        val_off[l] = off; off += (size_t)caps[l] * 128; off = (off + 255) & ~(size_t)255;
    }

    int* cnt = (int*)ws;
    float* poolsh = (float*)(ws + pool_off);
    float* dummy = (float*)(ws + 128);
    float* wt = (float*)(ws + wt_off);

    hipMemsetAsync(ws, 0, 32768, stream);   // cnt + pool shards

    k_f0<<<1024 + 468, 256, 0, stream>>>(
        (const float4*)mask, (int*)(ws + idx_off[0]), (int*)(ws + coord0_off),
        cnt, caps[0], wsrc, wt);

    k_f1<<<3096, 256, 0, stream>>>(
        (const int*)(ws + idx_off[0]), (int*)(ws + idx_off[1]), (int*)(ws + nbr_off[1]),
        cnt + 1, caps[1],
        x, w1, (const int*)(ws + coord0_off), cnt, caps[0],
        (float*)(ws + val_off[0]), poolsh, wm1, wm2, dummy);

    for (int i = 2; i <= 10; i++) {
        int lc = i - 1;
        int Hout = 1 << Hb[i];
        int S4 = (Hout * Hout + 3) >> 2;
        int downB = (S4 + 255) >> 8; if (downB < 1) downB = 1;
        int convB = (caps[lc] + 15) >> 4;
        k_flevel<<<downB + convB, 256, 0, stream>>>(
            downB,
            (const int*)(ws + idx_off[i - 1]), Hb[i - 1],
            (int*)(ws + idx_off[i]), (int*)(ws + nbr_off[i]), cnt + i, Hb[i], caps[i],
            (const float*)(ws + val_off[lc - 1]), wt + (size_t)(lc - 1) * 9216,
            (const int*)(ws + nbr_off[lc]), cnt + lc, caps[lc],
            (float*)(ws + val_off[lc]), poolsh + lc * 32);
    }

    k_tail<<<1, 1024, 0, stream>>>(
        cnt, poolsh,
        (const float*)(ws + val_off[9]), (const int*)(ws + nbr_off[10]),
        (const int*)(ws + idx_off[10]), wt,
        wm1, bm1, wm2, bm2, out);
}